// Round 1
// baseline (192.074 us; speedup 1.0000x reference)
//
#include <hip/hip_runtime.h>

#define NB 192
#define DD 128
#define RR 32

typedef __attribute__((ext_vector_type(8))) short bf16x8;
typedef __attribute__((ext_vector_type(4))) float f32x4;

template<int M> struct IC { static constexpr int value = M; };

__device__ __forceinline__ unsigned short f2bf(float x) {
  union { float f; unsigned int u; } c; c.f = x;
  unsigned int r = c.u + 0x7FFFu + ((c.u >> 16) & 1u);
  return (unsigned short)(r >> 16);
}
__device__ __forceinline__ float bf2f(unsigned short u) {
  union { unsigned int u; float f; } c; c.u = ((unsigned int)u) << 16;
  return c.f;
}
// XOR-swizzled H addressing (ushort index). hb = byte offset within 256B row.
__device__ __forceinline__ int haddr(int j, int hb) {
  return j * 128 + ((hb ^ ((j & 7) << 4)) >> 1);
}

__global__ __launch_bounds__(512) void cg_kernel(
    const float* __restrict__ node_s, const float* __restrict__ node_v,
    const float* __restrict__ rbf, const float* __restrict__ r_hat,
    const float* __restrict__ mask,
    const float* __restrict__ Ws1, const float* __restrict__ bs1,
    const float* __restrict__ Ws2, const float* __restrict__ bs2,
    const float* __restrict__ Wd1, const float* __restrict__ bd1,
    const float* __restrict__ Wd2, const float* __restrict__ bd2,
    const float* __restrict__ Wv1, const float* __restrict__ bv1,
    const float* __restrict__ Wv2, const float* __restrict__ bv2,
    const float* __restrict__ Wt1, const float* __restrict__ bt1,
    const float* __restrict__ Wt2, const float* __restrict__ bt2,
    const float* __restrict__ ln_g, const float* __restrict__ ln_b,
    const float* __restrict__ Wo, const float* __restrict__ bo,
    const float* __restrict__ v_scale, const float* __restrict__ t_scale,
    float* __restrict__ out)
{
  __shared__ __align__(16) char smem[64896];
  unsigned short* Rb  = (unsigned short*)smem;             // [192*32] bf16 rbf tile
  unsigned short* Hu  = (unsigned short*)(smem + 12288);   // [192*128] bf16 hidden (xor swizzled)
  unsigned short* YYu = (unsigned short*)(smem + 61440);   // 9 planes [192] bf16
  float* PR = (float*)smem;                                 // [2][128][10] aliases Rb (post-MLP)
  float* Xv = (float*)(smem + 12288);                       // [128] aliases H (post-MLP)
  float* XN = (float*)(smem + 12800);                       // [128]
  float* PS = (float*)(smem + 13312);                       // [4][128]
  float* ST = (float*)(smem + 15360);                       // [2]

  const int tid  = threadIdx.x;
  const int bi   = blockIdx.x;           // b*N + i
  const int b    = bi / NB;
  const int wid  = tid >> 6;
  const int lane = tid & 63;
  const int g = lane >> 4, ln = lane & 15;

  // ---- stage rbf row -> Rb (bf16) ----
  {
    const float4* rrow = (const float4*)(rbf + (size_t)bi * (NB * RR));
    #pragma unroll
    for (int q = 0; q < 3; ++q) {
      int f = q * 512 + tid;             // 1536 float4 total
      float4 v = rrow[f];
      union { unsigned short u[4]; uint2 d; } p;
      p.u[0] = f2bf(v.x); p.u[1] = f2bf(v.y); p.u[2] = f2bf(v.z); p.u[3] = f2bf(v.w);
      *(uint2*)&Rb[4 * f] = p.d;
    }
  }
  // ---- Y1/Y2/mask tables (mask powers folded) ----
  if (tid < NB) {
    int j = tid;
    const float* rh = r_hat + ((size_t)bi * NB + j) * 3;
    float x = rh[0], y = rh[1], z = rh[2];
    float m = mask[(size_t)bi * NB + j];
    float inv = 1.0f / (sqrtf(x*x + y*y + z*z) + 1e-12f);
    x *= inv; y *= inv; z *= inv;
    float m2 = m * m;
    YYu[0*NB + j] = f2bf(0.48860252f * m * x);              // m*Y1
    YYu[1*NB + j] = f2bf(0.48860252f * m * y);
    YYu[2*NB + j] = f2bf(0.48860252f * m * z);
    YYu[3*NB + j] = f2bf(m);
    YYu[4*NB + j] = f2bf(1.09254843f * m2 * x * y);         // m^2*Y2
    YYu[5*NB + j] = f2bf(1.09254843f * m2 * y * z);
    YYu[6*NB + j] = f2bf(0.31539157f * m2 * (3.f * z * z - 1.f));
    YYu[7*NB + j] = f2bf(1.09254843f * m2 * x * z);
    YYu[8*NB + j] = f2bf(0.54627422f * m2 * (x*x - y*y));
  }
  __syncthreads();

  const int mq = wid & 1, nq = wid >> 1;
  const int c0 = nq * 32 + ln, c1 = c0 + 16;
  const float* nsb = node_s + (size_t)b * (NB * DD);
  const float* nvb = node_v + (size_t)bi * (3 * DD);
  float V00 = nvb[c0], V10 = nvb[DD + c0], V20 = nvb[2*DD + c0];
  float V01 = nvb[c1], V11 = nvb[DD + c1], V21 = nvb[2*DD + c1];

  float msgs0=0.f, msgs1=0.f, msgsv0=0.f, msgsv1=0.f;
  float dv0x=0,dv0y=0,dv0z=0, dv1x=0,dv1y=0,dv1z=0;
  float dt00=0,dt01=0,dt02=0,dt03=0,dt04=0;
  float dt10=0,dt11=0,dt12=0,dt13=0,dt14=0;

  const f32x4 zacc = {0.f, 0.f, 0.f, 0.f};

  auto run_mlp = [&](auto MC, const float* W1, const float* b1,
                     const float* W2, const float* b2) {
    constexpr int MODE = decltype(MC)::value;
    // ---- GEMM1 (transposed): hidden^T[h][j] = sum_r W1[r][h]*rbf[j][r] ----
    union { bf16x8 v; unsigned short u[8]; } a1;
    #pragma unroll
    for (int e = 0; e < 8; ++e)
      a1.u[e] = f2bf(W1[(8*g + e) * DD + 16*wid + ln]);
    float4 b1v = *(const float4*)(b1 + 16*wid + 4*g);
    #pragma unroll
    for (int nt = 0; nt < 12; ++nt) {
      int j = nt * 16 + ln;
      bf16x8 bb = *(const bf16x8*)&Rb[j * 32 + 8 * g];
      f32x4 h4 = __builtin_amdgcn_mfma_f32_16x16x32_bf16(a1.v, bb, zacc, 0, 0, 0);
      union { unsigned short u[4]; uint2 d; } hp;
      float x0 = h4[0] + b1v.x; hp.u[0] = f2bf(x0 * __builtin_amdgcn_rcpf(1.f + __expf(-x0)));
      float x1 = h4[1] + b1v.y; hp.u[1] = f2bf(x1 * __builtin_amdgcn_rcpf(1.f + __expf(-x1)));
      float x2 = h4[2] + b1v.z; hp.u[2] = f2bf(x2 * __builtin_amdgcn_rcpf(1.f + __expf(-x2)));
      float x3 = h4[3] + b1v.w; hp.u[3] = f2bf(x3 * __builtin_amdgcn_rcpf(1.f + __expf(-x3)));
      *(uint2*)&Hu[haddr(j, 32*wid + 8*g)] = hp.d;
    }
    __syncthreads();
    // ---- GEMM2 + fused j-reduction ----
    float b2c0 = b2[c0], b2c1 = b2[c1];
    union { bf16x8 v; unsigned short u[8]; } Bf[4][2];
    #pragma unroll
    for (int ks = 0; ks < 4; ++ks)
      #pragma unroll
      for (int t = 0; t < 2; ++t)
        #pragma unroll
        for (int e = 0; e < 8; ++e)
          Bf[ks][t].u[e] = f2bf(W2[(32*ks + 8*g + e) * DD + nq*32 + t*16 + ln]);
    #pragma unroll
    for (int mt = 0; mt < 6; ++mt) {
      int jb = (mq * 6 + mt) * 16;
      f32x4 acc0 = zacc, acc1 = zacc;
      #pragma unroll
      for (int ks = 0; ks < 4; ++ks) {
        bf16x8 a = *(const bf16x8*)&Hu[haddr(jb + ln, 64*ks + 16*g)];
        acc0 = __builtin_amdgcn_mfma_f32_16x16x32_bf16(a, Bf[ks][0].v, acc0, 0, 0, 0);
        acc1 = __builtin_amdgcn_mfma_f32_16x16x32_bf16(a, Bf[ks][1].v, acc1, 0, 0, 0);
      }
      #pragma unroll
      for (int r = 0; r < 4; ++r) {
        int j = jb + 4*g + r;
        float w0 = acc0[r] + b2c0, w1 = acc1[r] + b2c1;
        if constexpr (MODE == 0) {          // msg_s: m^2 * ns * w
          float m = bf2f(YYu[3*NB + j]);
          float m2 = m * m;
          float ns0 = nsb[j*DD + c0], ns1 = nsb[j*DD + c1];
          msgs0 += m2 * ns0 * w0; msgs1 += m2 * ns1 * w1;
        } else if constexpr (MODE == 1) {   // msg_s_from_v: (V . m*Y1) * w
          float yx = bf2f(YYu[0*NB + j]), yy = bf2f(YYu[1*NB + j]), yz = bf2f(YYu[2*NB + j]);
          msgsv0 += (V00*yx + V10*yy + V20*yz) * w0;
          msgsv1 += (V01*yx + V11*yy + V21*yz) * w1;
        } else if constexpr (MODE == 2) {   // delta_v: m^2*ns*w*Y1 = (m*ns*w)*(m*Y1)
          float yx = bf2f(YYu[0*NB + j]), yy = bf2f(YYu[1*NB + j]), yz = bf2f(YYu[2*NB + j]);
          float m = bf2f(YYu[3*NB + j]);
          float ns0 = nsb[j*DD + c0], ns1 = nsb[j*DD + c1];
          float t0 = m * ns0 * w0, t1 = m * ns1 * w1;
          dv0x += t0*yx; dv0y += t0*yy; dv0z += t0*yz;
          dv1x += t1*yx; dv1y += t1*yy; dv1z += t1*yz;
        } else {                             // delta_t: (ns*w)*(m^2*Y2)
          float ya = bf2f(YYu[4*NB + j]), yb = bf2f(YYu[5*NB + j]), yc = bf2f(YYu[6*NB + j]);
          float yd = bf2f(YYu[7*NB + j]), ye = bf2f(YYu[8*NB + j]);
          float ns0 = nsb[j*DD + c0], ns1 = nsb[j*DD + c1];
          float t0 = ns0 * w0, t1 = ns1 * w1;
          dt00 += t0*ya; dt01 += t0*yb; dt02 += t0*yc; dt03 += t0*yd; dt04 += t0*ye;
          dt10 += t1*ya; dt11 += t1*yb; dt12 += t1*yc; dt13 += t1*yd; dt14 += t1*ye;
        }
      }
    }
    __syncthreads();
  };

  run_mlp(IC<0>{}, Ws1, bs1, Ws2, bs2);
  run_mlp(IC<1>{}, Wd1, bd1, Wd2, bd2);
  run_mlp(IC<2>{}, Wv1, bv1, Wv2, bv2);
  run_mlp(IC<3>{}, Wt1, bt1, Wt2, bt2);

  // ---- cross-lane (g groups) reduction, then stash per-wave partials ----
  auto wred = [](float v) { v += __shfl_xor(v, 16); v += __shfl_xor(v, 32); return v; };
  float q0[10] = {msgs0, msgsv0, dv0x, dv0y, dv0z, dt00, dt01, dt02, dt03, dt04};
  float q1[10] = {msgs1, msgsv1, dv1x, dv1y, dv1z, dt10, dt11, dt12, dt13, dt14};
  #pragma unroll
  for (int k = 0; k < 10; ++k) { q0[k] = wred(q0[k]); q1[k] = wred(q1[k]); }
  if (g == 0) {
    float* p0 = PR + (mq * 128 + c0) * 10;
    float* p1 = PR + (mq * 128 + c1) * 10;
    #pragma unroll
    for (int k = 0; k < 10; ++k) { p0[k] = q0[k]; p1[k] = q1[k]; }
  }
  __syncthreads();

  // ---- combine halves, write delta_v / delta_t, build x for LN ----
  if (tid < DD) {
    float acc[10];
    const float* pa = PR + tid * 10;
    const float* pb = PR + (128 + tid) * 10;
    #pragma unroll
    for (int k = 0; k < 10; ++k) acc[k] = pa[k] + pb[k];
    float vs = v_scale[tid], ts = t_scale[tid];
    size_t vbase = 98304 + (size_t)bi * (3 * DD) + tid;
    out[vbase]         = acc[2] * vs;
    out[vbase + DD]    = acc[3] * vs;
    out[vbase + 2*DD]  = acc[4] * vs;
    size_t tbase = 393216 + (size_t)bi * (5 * DD) + tid;
    out[tbase]         = acc[5] * ts;
    out[tbase + DD]    = acc[6] * ts;
    out[tbase + 2*DD]  = acc[7] * ts;
    out[tbase + 3*DD]  = acc[8] * ts;
    out[tbase + 4*DD]  = acc[9] * ts;
    Xv[tid] = acc[0] + acc[1];
  }
  __syncthreads();
  if (tid < 64) {
    float a = Xv[tid], c = Xv[tid + 64];
    float s = a + c, ss = a*a + c*c;
    #pragma unroll
    for (int off = 32; off > 0; off >>= 1) {
      s  += __shfl_down(s, off);
      ss += __shfl_down(ss, off);
    }
    if (tid == 0) {
      float mu  = s * (1.f / 128.f);
      float var = ss * (1.f / 128.f) - mu * mu;
      ST[0] = mu; ST[1] = rsqrtf(var + 1e-5f);
    }
  }
  __syncthreads();
  if (tid < DD) XN[tid] = (Xv[tid] - ST[0]) * ST[1] * ln_g[tid] + ln_b[tid];
  __syncthreads();
  {
    int dp = tid & 127, p = tid >> 7;
    float s = 0.f;
    #pragma unroll
    for (int dd = 0; dd < 32; ++dd) {
      int d = p * 32 + dd;
      s += XN[d] * Wo[d * DD + dp];
    }
    PS[p * 128 + dp] = s;
  }
  __syncthreads();
  if (tid < DD)
    out[(size_t)bi * DD + tid] = PS[tid] + PS[128 + tid] + PS[256 + tid] + PS[384 + tid] + bo[tid];
}

extern "C" void kernel_launch(void* const* d_in, const int* in_sizes, int n_in,
                              void* d_out, int out_size, void* d_ws, size_t ws_size,
                              hipStream_t stream) {
  (void)in_sizes; (void)n_in; (void)d_ws; (void)ws_size; (void)out_size;
  const float* node_s = (const float*)d_in[0];
  const float* node_v = (const float*)d_in[1];
  // d_in[2] = node_t (unused by the math)
  const float* rbf    = (const float*)d_in[3];
  const float* r_hat  = (const float*)d_in[4];
  const float* mask   = (const float*)d_in[5];
  const float* Ws1 = (const float*)d_in[6];  const float* bs1 = (const float*)d_in[7];
  const float* Ws2 = (const float*)d_in[8];  const float* bs2 = (const float*)d_in[9];
  const float* Wd1 = (const float*)d_in[10]; const float* bd1 = (const float*)d_in[11];
  const float* Wd2 = (const float*)d_in[12]; const float* bd2 = (const float*)d_in[13];
  const float* Wv1 = (const float*)d_in[14]; const float* bv1 = (const float*)d_in[15];
  const float* Wv2 = (const float*)d_in[16]; const float* bv2 = (const float*)d_in[17];
  const float* Wt1 = (const float*)d_in[18]; const float* bt1 = (const float*)d_in[19];
  const float* Wt2 = (const float*)d_in[20]; const float* bt2 = (const float*)d_in[21];
  const float* ln_g = (const float*)d_in[22]; const float* ln_b = (const float*)d_in[23];
  const float* Wo   = (const float*)d_in[24]; const float* bo   = (const float*)d_in[25];
  const float* v_scale = (const float*)d_in[26];
  const float* t_scale = (const float*)d_in[27];
  float* outp = (float*)d_out;

  hipLaunchKernelGGL(cg_kernel, dim3(4 * NB), dim3(512), 0, stream,
                     node_s, node_v, rbf, r_hat, mask,
                     Ws1, bs1, Ws2, bs2, Wd1, bd1, Wd2, bd2,
                     Wv1, bv1, Wv2, bv2, Wt1, bt1, Wt2, bt2,
                     ln_g, ln_b, Wo, bo, v_scale, t_scale, outp);
}

// Round 2
// 159.119 us; speedup vs baseline: 1.2071x; 1.2071x over previous
//
#include <hip/hip_runtime.h>
#include <hip/hip_bf16.h>

#define NB 192
#define DD 128
#define RR 32
#define JB 96   // j rows per main-kernel block

typedef __attribute__((ext_vector_type(8))) short bf16x8;
typedef __attribute__((ext_vector_type(4))) float f32x4;

template<int M> struct IC { static constexpr int value = M; };

__device__ __forceinline__ unsigned short f2bf(float x) {
  union { __hip_bfloat16 h; unsigned short u; } c;
  c.h = __float2bfloat16(x);
  return c.u;
}
__device__ __forceinline__ float bf2f(unsigned short u) {
  union { unsigned int u; float f; } c; c.u = ((unsigned int)u) << 16;
  return c.f;
}
// XOR-swizzled H addressing (ushort index). hb = byte offset within 256B row.
__device__ __forceinline__ int haddr(int j, int hb) {
  return j * 128 + ((hb ^ ((j & 7) << 4)) >> 1);
}

__global__ __launch_bounds__(256, 4) void cg_main(
    const float* __restrict__ node_s, const float* __restrict__ node_v,
    const float* __restrict__ rbf, const float* __restrict__ r_hat,
    const float* __restrict__ mask,
    const float* __restrict__ Ws1, const float* __restrict__ bs1,
    const float* __restrict__ Ws2, const float* __restrict__ bs2,
    const float* __restrict__ Wd1, const float* __restrict__ bd1,
    const float* __restrict__ Wd2, const float* __restrict__ bd2,
    const float* __restrict__ Wv1, const float* __restrict__ bv1,
    const float* __restrict__ Wv2, const float* __restrict__ bv2,
    const float* __restrict__ Wt1, const float* __restrict__ bt1,
    const float* __restrict__ Wt2, const float* __restrict__ bt2,
    float* __restrict__ ws)
{
  __shared__ __align__(16) char smem[32448];
  unsigned short* Rb  = (unsigned short*)smem;             // [96*32] bf16 rbf tile
  unsigned short* Hu  = (unsigned short*)(smem + 6144);    // [96*128] bf16 hidden (xor swizzled)
  unsigned short* YYu = (unsigned short*)(smem + 30720);   // 9 planes [96] bf16

  const int tid  = threadIdx.x;
  const int bx   = blockIdx.x;
  const int bi   = bx >> 1;             // b*N + i
  const int jh   = bx & 1;
  const int j0   = jh * JB;
  const int b    = bi / NB;
  const int wid  = tid >> 6;            // 0..3
  const int lane = tid & 63;
  const int g = lane >> 4, ln = lane & 15;

  // ---- stage rbf half-row -> Rb (bf16) ----
  {
    const float4* rrow = (const float4*)(rbf + (size_t)bi * (NB * RR) + j0 * RR);
    #pragma unroll
    for (int q = 0; q < 3; ++q) {
      int f = q * 256 + tid;            // 768 float4 total
      float4 v = rrow[f];
      union { unsigned short u[4]; uint2 d; } p;
      p.u[0] = f2bf(v.x); p.u[1] = f2bf(v.y); p.u[2] = f2bf(v.z); p.u[3] = f2bf(v.w);
      *(uint2*)&Rb[4 * f] = p.d;
    }
  }
  // ---- Y1/Y2/mask tables (mask powers folded) ----
  if (tid < JB) {
    int jj = j0 + tid;
    const float* rh = r_hat + ((size_t)bi * NB + jj) * 3;
    float x = rh[0], y = rh[1], z = rh[2];
    float m = mask[(size_t)bi * NB + jj];
    float inv = 1.0f / (sqrtf(x*x + y*y + z*z) + 1e-12f);
    x *= inv; y *= inv; z *= inv;
    float m2 = m * m;
    YYu[0*JB + tid] = f2bf(0.48860252f * m * x);            // m*Y1
    YYu[1*JB + tid] = f2bf(0.48860252f * m * y);
    YYu[2*JB + tid] = f2bf(0.48860252f * m * z);
    YYu[3*JB + tid] = f2bf(m);
    YYu[4*JB + tid] = f2bf(1.09254843f * m2 * x * y);       // m^2*Y2
    YYu[5*JB + tid] = f2bf(1.09254843f * m2 * y * z);
    YYu[6*JB + tid] = f2bf(0.31539157f * m2 * (3.f * z * z - 1.f));
    YYu[7*JB + tid] = f2bf(1.09254843f * m2 * x * z);
    YYu[8*JB + tid] = f2bf(0.54627422f * m2 * (x*x - y*y));
  }
  __syncthreads();

  const int c0 = wid * 32 + ln, c1 = c0 + 16;
  const float* nsb = node_s + (size_t)b * (NB * DD);
  const float* nvb = node_v + (size_t)bi * (3 * DD);
  float V00 = nvb[c0], V10 = nvb[DD + c0], V20 = nvb[2*DD + c0];
  float V01 = nvb[c1], V11 = nvb[DD + c1], V21 = nvb[2*DD + c1];

  float msgs0=0.f, msgs1=0.f, msgsv0=0.f, msgsv1=0.f;
  float dv0x=0,dv0y=0,dv0z=0, dv1x=0,dv1y=0,dv1z=0;
  float dt00=0,dt01=0,dt02=0,dt03=0,dt04=0;
  float dt10=0,dt11=0,dt12=0,dt13=0,dt14=0;

  const f32x4 zacc = {0.f, 0.f, 0.f, 0.f};

  auto run_mlp = [&](auto MC, const float* W1, const float* b1,
                     const float* W2, const float* b2) {
    constexpr int MODE = decltype(MC)::value;
    // ---- GEMM1 (transposed): hidden^T[h][j] = sum_r W1[r][h]*rbf[j][r] ----
    #pragma unroll
    for (int t = 0; t < 2; ++t) {
      const int ht = 2 * wid + t;
      union { bf16x8 v; unsigned short u[8]; } a1;
      #pragma unroll
      for (int e = 0; e < 8; ++e)
        a1.u[e] = f2bf(W1[(8*g + e) * DD + ht*16 + ln]);
      float4 b1v = *(const float4*)(b1 + ht*16 + 4*g);
      #pragma unroll
      for (int nt = 0; nt < 6; ++nt) {
        int j = nt * 16 + ln;
        bf16x8 bb = *(const bf16x8*)&Rb[j * 32 + 8 * g];
        f32x4 h4 = __builtin_amdgcn_mfma_f32_16x16x32_bf16(a1.v, bb, zacc, 0, 0, 0);
        union { unsigned short u[4]; uint2 d; } hp;
        float x0 = h4[0] + b1v.x; hp.u[0] = f2bf(x0 * __builtin_amdgcn_rcpf(1.f + __expf(-x0)));
        float x1 = h4[1] + b1v.y; hp.u[1] = f2bf(x1 * __builtin_amdgcn_rcpf(1.f + __expf(-x1)));
        float x2 = h4[2] + b1v.z; hp.u[2] = f2bf(x2 * __builtin_amdgcn_rcpf(1.f + __expf(-x2)));
        float x3 = h4[3] + b1v.w; hp.u[3] = f2bf(x3 * __builtin_amdgcn_rcpf(1.f + __expf(-x3)));
        *(uint2*)&Hu[haddr(j, ht*32 + 8*g)] = hp.d;
      }
    }
    __syncthreads();
    // ---- GEMM2 + fused j-reduction ----
    float b2c0 = b2[c0], b2c1 = b2[c1];
    union { bf16x8 v; unsigned short u[8]; } Bf[4][2];
    #pragma unroll
    for (int ks = 0; ks < 4; ++ks)
      #pragma unroll
      for (int t = 0; t < 2; ++t)
        #pragma unroll
        for (int e = 0; e < 8; ++e)
          Bf[ks][t].u[e] = f2bf(W2[(32*ks + 8*g + e) * DD + wid*32 + t*16 + ln]);
    #pragma unroll
    for (int mt = 0; mt < 6; ++mt) {
      int jb = mt * 16;
      f32x4 acc0 = zacc, acc1 = zacc;
      #pragma unroll
      for (int ks = 0; ks < 4; ++ks) {
        bf16x8 a = *(const bf16x8*)&Hu[haddr(jb + ln, 64*ks + 16*g)];
        acc0 = __builtin_amdgcn_mfma_f32_16x16x32_bf16(a, Bf[ks][0].v, acc0, 0, 0, 0);
        acc1 = __builtin_amdgcn_mfma_f32_16x16x32_bf16(a, Bf[ks][1].v, acc1, 0, 0, 0);
      }
      #pragma unroll
      for (int r = 0; r < 4; ++r) {
        int j = jb + 4*g + r;
        int jj = j0 + j;
        float w0 = acc0[r] + b2c0, w1 = acc1[r] + b2c1;
        if constexpr (MODE == 0) {          // msg_s: m^2 * ns * w
          float m = bf2f(YYu[3*JB + j]);
          float m2 = m * m;
          float ns0 = nsb[(size_t)jj*DD + c0], ns1 = nsb[(size_t)jj*DD + c1];
          msgs0 += m2 * ns0 * w0; msgs1 += m2 * ns1 * w1;
        } else if constexpr (MODE == 1) {   // msg_s_from_v: (V . m*Y1) * w
          float yx = bf2f(YYu[0*JB + j]), yy = bf2f(YYu[1*JB + j]), yz = bf2f(YYu[2*JB + j]);
          msgsv0 += (V00*yx + V10*yy + V20*yz) * w0;
          msgsv1 += (V01*yx + V11*yy + V21*yz) * w1;
        } else if constexpr (MODE == 2) {   // delta_v: (m*ns*w)*(m*Y1)
          float yx = bf2f(YYu[0*JB + j]), yy = bf2f(YYu[1*JB + j]), yz = bf2f(YYu[2*JB + j]);
          float m = bf2f(YYu[3*JB + j]);
          float ns0 = nsb[(size_t)jj*DD + c0], ns1 = nsb[(size_t)jj*DD + c1];
          float t0 = m * ns0 * w0, t1 = m * ns1 * w1;
          dv0x += t0*yx; dv0y += t0*yy; dv0z += t0*yz;
          dv1x += t1*yx; dv1y += t1*yy; dv1z += t1*yz;
        } else {                             // delta_t: (ns*w)*(m^2*Y2)
          float ya = bf2f(YYu[4*JB + j]), yb = bf2f(YYu[5*JB + j]), yc = bf2f(YYu[6*JB + j]);
          float yd = bf2f(YYu[7*JB + j]), ye = bf2f(YYu[8*JB + j]);
          float ns0 = nsb[(size_t)jj*DD + c0], ns1 = nsb[(size_t)jj*DD + c1];
          float t0 = ns0 * w0, t1 = ns1 * w1;
          dt00 += t0*ya; dt01 += t0*yb; dt02 += t0*yc; dt03 += t0*yd; dt04 += t0*ye;
          dt10 += t1*ya; dt11 += t1*yb; dt12 += t1*yc; dt13 += t1*yd; dt14 += t1*ye;
        }
      }
    }
    __syncthreads();
  };

  run_mlp(IC<0>{}, Ws1, bs1, Ws2, bs2);
  run_mlp(IC<1>{}, Wd1, bd1, Wd2, bd2);
  run_mlp(IC<2>{}, Wv1, bv1, Wv2, bv2);
  run_mlp(IC<3>{}, Wt1, bt1, Wt2, bt2);

  // ---- in-wave reduction over g groups; each wave owns distinct 32 cols ----
  auto wred = [](float v) { v += __shfl_xor(v, 16); v += __shfl_xor(v, 32); return v; };
  float q0[10] = {msgs0, msgsv0, dv0x, dv0y, dv0z, dt00, dt01, dt02, dt03, dt04};
  float q1[10] = {msgs1, msgsv1, dv1x, dv1y, dv1z, dt10, dt11, dt12, dt13, dt14};
  #pragma unroll
  for (int k = 0; k < 10; ++k) { q0[k] = wred(q0[k]); q1[k] = wred(q1[k]); }
  if (g == 0) {
    float* w0 = ws + (size_t)bx * 1280;
    #pragma unroll
    for (int k = 0; k < 10; ++k) {
      w0[k*128 + c0] = q0[k];
      w0[k*128 + c1] = q1[k];
    }
  }
}

__global__ __launch_bounds__(256) void cg_final(
    const float* __restrict__ ws,
    const float* __restrict__ ln_g, const float* __restrict__ ln_b,
    const float* __restrict__ Wo, const float* __restrict__ bo,
    const float* __restrict__ v_scale, const float* __restrict__ t_scale,
    float* __restrict__ out)
{
  __shared__ float Xv[128];
  __shared__ float XN[128];
  __shared__ float PS[2][128];
  __shared__ float ST[2];
  const int bi = blockIdx.x;
  const int tid = threadIdx.x;

  if (tid < 128) {
    const float* pa = ws + (size_t)(bi * 2) * 1280;
    const float* pb = pa + 1280;
    float acc[10];
    #pragma unroll
    for (int k = 0; k < 10; ++k) acc[k] = pa[k*128 + tid] + pb[k*128 + tid];
    float vs = v_scale[tid], ts = t_scale[tid];
    size_t vbase = 98304 + (size_t)bi * (3 * DD) + tid;
    out[vbase]        = acc[2] * vs;
    out[vbase + DD]   = acc[3] * vs;
    out[vbase + 2*DD] = acc[4] * vs;
    size_t tbase = 393216 + (size_t)bi * (5 * DD) + tid;
    out[tbase]        = acc[5] * ts;
    out[tbase + DD]   = acc[6] * ts;
    out[tbase + 2*DD] = acc[7] * ts;
    out[tbase + 3*DD] = acc[8] * ts;
    out[tbase + 4*DD] = acc[9] * ts;
    Xv[tid] = acc[0] + acc[1];
  }
  __syncthreads();
  if (tid < 64) {
    float a = Xv[tid], c = Xv[tid + 64];
    float s = a + c, ss = a*a + c*c;
    #pragma unroll
    for (int off = 32; off > 0; off >>= 1) {
      s  += __shfl_down(s, off);
      ss += __shfl_down(ss, off);
    }
    if (tid == 0) {
      float mu  = s * (1.f / 128.f);
      float var = ss * (1.f / 128.f) - mu * mu;
      ST[0] = mu; ST[1] = rsqrtf(var + 1e-5f);
    }
  }
  __syncthreads();
  if (tid < 128) XN[tid] = (Xv[tid] - ST[0]) * ST[1] * ln_g[tid] + ln_b[tid];
  __syncthreads();
  {
    int dp = tid & 127, p = tid >> 7;   // p in {0,1}
    float s = 0.f;
    #pragma unroll
    for (int dd = 0; dd < 64; ++dd) {
      int d = p * 64 + dd;
      s += XN[d] * Wo[d * DD + dp];
    }
    PS[p][dp] = s;
  }
  __syncthreads();
  if (tid < 128)
    out[(size_t)bi * DD + tid] = PS[0][tid] + PS[1][tid] + bo[tid];
}

extern "C" void kernel_launch(void* const* d_in, const int* in_sizes, int n_in,
                              void* d_out, int out_size, void* d_ws, size_t ws_size,
                              hipStream_t stream) {
  (void)in_sizes; (void)n_in; (void)ws_size; (void)out_size;
  const float* node_s = (const float*)d_in[0];
  const float* node_v = (const float*)d_in[1];
  // d_in[2] = node_t (unused by the math)
  const float* rbf    = (const float*)d_in[3];
  const float* r_hat  = (const float*)d_in[4];
  const float* mask   = (const float*)d_in[5];
  const float* Ws1 = (const float*)d_in[6];  const float* bs1 = (const float*)d_in[7];
  const float* Ws2 = (const float*)d_in[8];  const float* bs2 = (const float*)d_in[9];
  const float* Wd1 = (const float*)d_in[10]; const float* bd1 = (const float*)d_in[11];
  const float* Wd2 = (const float*)d_in[12]; const float* bd2 = (const float*)d_in[13];
  const float* Wv1 = (const float*)d_in[14]; const float* bv1 = (const float*)d_in[15];
  const float* Wv2 = (const float*)d_in[16]; const float* bv2 = (const float*)d_in[17];
  const float* Wt1 = (const float*)d_in[18]; const float* bt1 = (const float*)d_in[19];
  const float* Wt2 = (const float*)d_in[20]; const float* bt2 = (const float*)d_in[21];
  const float* ln_g = (const float*)d_in[22]; const float* ln_b = (const float*)d_in[23];
  const float* Wo   = (const float*)d_in[24]; const float* bo   = (const float*)d_in[25];
  const float* v_scale = (const float*)d_in[26];
  const float* t_scale = (const float*)d_in[27];
  float* outp = (float*)d_out;
  float* wsf  = (float*)d_ws;   // needs 1536*1280*4 = 7.86 MB

  hipLaunchKernelGGL(cg_main, dim3(2 * 4 * NB), dim3(256), 0, stream,
                     node_s, node_v, rbf, r_hat, mask,
                     Ws1, bs1, Ws2, bs2, Wd1, bd1, Wd2, bd2,
                     Wv1, bv1, Wv2, bv2, Wt1, bt1, Wt2, bt2, wsf);
  hipLaunchKernelGGL(cg_final, dim3(4 * NB), dim3(256), 0, stream,
                     wsf, ln_g, ln_b, Wo, bo, v_scale, t_scale, outp);
}

// Round 3
// 71.756 us; speedup vs baseline: 2.6768x; 2.2175x over previous
//
#include <hip/hip_runtime.h>
#include <hip/hip_bf16.h>

#define NB 192
#define DD 128
#define RR 32

typedef __attribute__((ext_vector_type(8))) short bf16x8;
typedef __attribute__((ext_vector_type(4))) float f32x4;

template<int M> struct IC { static constexpr int value = M; };

__device__ __forceinline__ unsigned short f2bf(float x) {
  union { __hip_bfloat16 h; unsigned short u; } c;
  c.h = __float2bfloat16(x);
  return c.u;
}
__device__ __forceinline__ float bf2f(unsigned short u) {
  union { unsigned int u; float f; } c; c.u = ((unsigned int)u) << 16;
  return c.f;
}

// ---------------- weight fragment prep (runs every call, ~11K threads) ----
__global__ __launch_bounds__(256) void cg_prep(
    const float* __restrict__ Ws1, const float* __restrict__ Wd1,
    const float* __restrict__ Wv1, const float* __restrict__ Wt1,
    const float* __restrict__ Ws2, const float* __restrict__ Wd2,
    const float* __restrict__ Wv2, const float* __restrict__ Wt2,
    const float* __restrict__ bs1, const float* __restrict__ bd1,
    const float* __restrict__ bv1, const float* __restrict__ bt1,
    const float* __restrict__ bs2, const float* __restrict__ bd2,
    const float* __restrict__ bv2, const float* __restrict__ bt2,
    unsigned short* __restrict__ w1f, unsigned short* __restrict__ w2f,
    float* __restrict__ bcat1, float* __restrict__ bcat2)
{
  const float* W1s[4] = {Ws1, Wd1, Wv1, Wt1};
  const float* W2s[4] = {Ws2, Wd2, Wv2, Wt2};
  const float* B1s[4] = {bs1, bd1, bv1, bt1};
  const float* B2s[4] = {bs2, bd2, bv2, bt2};
  int t = blockIdx.x * 256 + threadIdx.x;
  if (t < 2048) {
    // w1f fragment f = mlp*8 + htl ; slot (f*64+lane)*8+e
    int lane = t & 63, f = t >> 6;
    int mlp = f >> 3, htl = f & 7;
    int g = lane >> 4, ln = lane & 15;
    const float* W = W1s[mlp];
    union { unsigned short u[8]; uint4 d; } p;
    #pragma unroll
    for (int e = 0; e < 8; ++e)
      p.u[e] = f2bf(W[(8*g + e) * DD + htl*16 + ln]);
    *(uint4*)&w1f[t * 8] = p.d;
  } else if (t < 10240) {
    // w2f fragment f = (mlp*4+ks)*8 + ct
    int t2 = t - 2048;
    int lane = t2 & 63, f = t2 >> 6;
    int ct = f & 7, ks = (f >> 3) & 3, mlp = f >> 5;
    int g = lane >> 4, ln = lane & 15;
    const float* W = W2s[mlp];
    union { unsigned short u[8]; uint4 d; } p;
    #pragma unroll
    for (int e = 0; e < 8; ++e)
      p.u[e] = f2bf(W[(32*ks + 8*g + e) * DD + ct*16 + ln]);
    *(uint4*)&w2f[t2 * 8] = p.d;
  } else if (t < 10752) {
    int t3 = t - 10240;
    bcat1[t3] = B1s[t3 >> 7][t3 & 127];
  } else if (t < 11264) {
    int t3 = t - 10752;
    bcat2[t3] = B2s[t3 >> 7][t3 & 127];
  }
}

// ---------------- main kernel ------------------------------------------
// JBLK = j rows per block; MPP = MLPs batched per pass (Hu width MPP*128)
template<int JBLK, int MPP>
__global__ __launch_bounds__(256, 3) void cg_main(
    const float* __restrict__ node_s, const float* __restrict__ node_v,
    const float* __restrict__ rbf, const float* __restrict__ r_hat,
    const float* __restrict__ mask,
    const unsigned short* __restrict__ w1f, const unsigned short* __restrict__ w2f,
    const float* __restrict__ bcat1, const float* __restrict__ bcat2,
    float* __restrict__ ws)
{
  constexpr int NSPLIT = NB / JBLK;
  constexpr int NPASS  = 4 / MPP;
  constexpr int NT     = JBLK / 16;
  constexpr int HROW   = MPP * 128;            // ushorts per Hu row
  constexpr int RB_B   = JBLK * 32 * 2;
  constexpr int HU_B   = JBLK * HROW * 2;
  __shared__ __align__(16) char smem[RB_B + HU_B + 9 * JBLK * 2];
  unsigned short* Rb  = (unsigned short*)smem;
  unsigned short* Hu  = (unsigned short*)(smem + RB_B);
  unsigned short* YYu = (unsigned short*)(smem + RB_B + HU_B);

  const int tid  = threadIdx.x;
  const int bx   = blockIdx.x;
  const int bi   = bx / NSPLIT;
  const int j0   = (bx % NSPLIT) * JBLK;
  const int b    = bi / NB;
  const int wid  = tid >> 6;
  const int lane = tid & 63;
  const int g = lane >> 4, ln = lane & 15;

  auto haddr = [](int j, int hb) {             // hb = byte col in Hu row
    return j * HROW + (((hb) ^ ((j & 7) << 4)) >> 1);
  };

  // ---- stage rbf rows -> Rb (bf16) ----
  {
    const float4* rrow = (const float4*)(rbf + (size_t)bi * (NB * RR) + j0 * RR);
    #pragma unroll
    for (int f = tid; f < JBLK * 8; f += 256) {
      float4 v = rrow[f];
      union { unsigned short u[4]; uint2 d; } p;
      p.u[0] = f2bf(v.x); p.u[1] = f2bf(v.y); p.u[2] = f2bf(v.z); p.u[3] = f2bf(v.w);
      *(uint2*)&Rb[4 * f] = p.d;
    }
  }
  // ---- Y1/Y2/mask tables ----
  if (tid < JBLK) {
    int jj = j0 + tid;
    const float* rh = r_hat + ((size_t)bi * NB + jj) * 3;
    float x = rh[0], y = rh[1], z = rh[2];
    float m = mask[(size_t)bi * NB + jj];
    float inv = 1.0f / (sqrtf(x*x + y*y + z*z) + 1e-12f);
    x *= inv; y *= inv; z *= inv;
    float m2 = m * m;
    YYu[0*JBLK + tid] = f2bf(0.48860252f * m * x);
    YYu[1*JBLK + tid] = f2bf(0.48860252f * m * y);
    YYu[2*JBLK + tid] = f2bf(0.48860252f * m * z);
    YYu[3*JBLK + tid] = f2bf(m);
    YYu[4*JBLK + tid] = f2bf(1.09254843f * m2 * x * y);
    YYu[5*JBLK + tid] = f2bf(1.09254843f * m2 * y * z);
    YYu[6*JBLK + tid] = f2bf(0.31539157f * m2 * (3.f * z * z - 1.f));
    YYu[7*JBLK + tid] = f2bf(1.09254843f * m2 * x * z);
    YYu[8*JBLK + tid] = f2bf(0.54627422f * m2 * (x*x - y*y));
  }
  __syncthreads();

  const int c0 = wid * 32 + ln, c1 = c0 + 16;
  const float* nsb = node_s + (size_t)b * (NB * DD);
  const float* nvb = node_v + (size_t)bi * (3 * DD);
  float V00 = nvb[c0], V10 = nvb[DD + c0], V20 = nvb[2*DD + c0];
  float V01 = nvb[c1], V11 = nvb[DD + c1], V21 = nvb[2*DD + c1];

  float msgs0=0.f, msgs1=0.f, msgsv0=0.f, msgsv1=0.f;
  float dv0x=0,dv0y=0,dv0z=0, dv1x=0,dv1y=0,dv1z=0;
  float dt00=0,dt01=0,dt02=0,dt03=0,dt04=0;
  float dt10=0,dt11=0,dt12=0,dt13=0,dt14=0;

  const f32x4 zacc = {0.f, 0.f, 0.f, 0.f};

  auto do_pass = [&](auto PC) {
    constexpr int PASS = decltype(PC)::value;
    // ---- GEMM1 (batched over MPP MLPs): Hu[j][h] = silu(rbf @ W1 + b1) ----
    #pragma unroll
    for (int q = 0; q < MPP * 2; ++q) {
      const int idx  = wid * (MPP * 2) + q;   // tile index within pass
      const int lm   = idx >> 3;              // local mlp
      const int htl  = idx & 7;               // h-tile within mlp
      const int f    = PASS * MPP * 8 + idx;  // w1f fragment id
      bf16x8 a1 = *(const bf16x8*)&w1f[(f * 64 + lane) * 8];
      float4 b1v = *(const float4*)(bcat1 + (PASS*MPP + lm) * DD + htl*16 + 4*g);
      #pragma unroll
      for (int nt = 0; nt < NT; ++nt) {
        int j = nt * 16 + ln;
        bf16x8 bb = *(const bf16x8*)&Rb[j * 32 + 8 * g];
        f32x4 h4 = __builtin_amdgcn_mfma_f32_16x16x32_bf16(a1, bb, zacc, 0, 0, 0);
        union { unsigned short u[4]; uint2 d; } hp;
        float x0 = h4[0] + b1v.x; hp.u[0] = f2bf(x0 * __builtin_amdgcn_rcpf(1.f + __expf(-x0)));
        float x1 = h4[1] + b1v.y; hp.u[1] = f2bf(x1 * __builtin_amdgcn_rcpf(1.f + __expf(-x1)));
        float x2 = h4[2] + b1v.z; hp.u[2] = f2bf(x2 * __builtin_amdgcn_rcpf(1.f + __expf(-x2)));
        float x3 = h4[3] + b1v.w; hp.u[3] = f2bf(x3 * __builtin_amdgcn_rcpf(1.f + __expf(-x3)));
        *(uint2*)&Hu[haddr(j, lm*256 + htl*32 + 8*g)] = hp.d;
      }
    }
    __syncthreads();
    // ---- GEMM2 + fused j-reduction, one LM at a time ----
    auto g2 = [&](auto LC) {
      constexpr int LM   = decltype(LC)::value;
      constexpr int MODE = PASS * MPP + LM;   // 0=s 1=d 2=v 3=t
      float b2c0 = bcat2[MODE * DD + c0], b2c1 = bcat2[MODE * DD + c1];
      bf16x8 Bf[4][2];
      #pragma unroll
      for (int ks = 0; ks < 4; ++ks)
        #pragma unroll
        for (int t = 0; t < 2; ++t) {
          int f2 = (MODE * 4 + ks) * 8 + 2 * wid + t;
          Bf[ks][t] = *(const bf16x8*)&w2f[(f2 * 64 + lane) * 8];
        }
      #pragma unroll
      for (int mt = 0; mt < NT; ++mt) {
        int jb = mt * 16;
        f32x4 acc0 = zacc, acc1 = zacc;
        #pragma unroll
        for (int ks = 0; ks < 4; ++ks) {
          bf16x8 a = *(const bf16x8*)&Hu[haddr(jb + ln, LM*256 + ks*64 + 16*g)];
          acc0 = __builtin_amdgcn_mfma_f32_16x16x32_bf16(a, Bf[ks][0], acc0, 0, 0, 0);
          acc1 = __builtin_amdgcn_mfma_f32_16x16x32_bf16(a, Bf[ks][1], acc1, 0, 0, 0);
        }
        #pragma unroll
        for (int r = 0; r < 4; ++r) {
          int j = jb + 4*g + r;
          int jj = j0 + j;
          float w0 = acc0[r] + b2c0, w1 = acc1[r] + b2c1;
          if constexpr (MODE == 0) {
            float m = bf2f(YYu[3*JBLK + j]);
            float m2 = m * m;
            float ns0 = nsb[(size_t)jj*DD + c0], ns1 = nsb[(size_t)jj*DD + c1];
            msgs0 += m2 * ns0 * w0; msgs1 += m2 * ns1 * w1;
          } else if constexpr (MODE == 1) {
            float yx = bf2f(YYu[0*JBLK + j]), yy = bf2f(YYu[1*JBLK + j]), yz = bf2f(YYu[2*JBLK + j]);
            msgsv0 += (V00*yx + V10*yy + V20*yz) * w0;
            msgsv1 += (V01*yx + V11*yy + V21*yz) * w1;
          } else if constexpr (MODE == 2) {
            float yx = bf2f(YYu[0*JBLK + j]), yy = bf2f(YYu[1*JBLK + j]), yz = bf2f(YYu[2*JBLK + j]);
            float m = bf2f(YYu[3*JBLK + j]);
            float ns0 = nsb[(size_t)jj*DD + c0], ns1 = nsb[(size_t)jj*DD + c1];
            float t0 = m * ns0 * w0, t1 = m * ns1 * w1;
            dv0x += t0*yx; dv0y += t0*yy; dv0z += t0*yz;
            dv1x += t1*yx; dv1y += t1*yy; dv1z += t1*yz;
          } else {
            float ya = bf2f(YYu[4*JBLK + j]), yb = bf2f(YYu[5*JBLK + j]), yc = bf2f(YYu[6*JBLK + j]);
            float yd = bf2f(YYu[7*JBLK + j]), ye = bf2f(YYu[8*JBLK + j]);
            float ns0 = nsb[(size_t)jj*DD + c0], ns1 = nsb[(size_t)jj*DD + c1];
            float t0 = ns0 * w0, t1 = ns1 * w1;
            dt00 += t0*ya; dt01 += t0*yb; dt02 += t0*yc; dt03 += t0*yd; dt04 += t0*ye;
            dt10 += t1*ya; dt11 += t1*yb; dt12 += t1*yc; dt13 += t1*yd; dt14 += t1*ye;
          }
        }
      }
    };
    g2(IC<0>{});
    g2(IC<1>{});
    if constexpr (MPP > 2) { g2(IC<2>{}); g2(IC<3>{}); }
    __syncthreads();
  };

  do_pass(IC<0>{});
  if constexpr (NPASS > 1) do_pass(IC<1>{});

  // ---- in-wave reduction over g groups; waves own distinct 32 cols ----
  auto wred = [](float v) { v += __shfl_xor(v, 16); v += __shfl_xor(v, 32); return v; };
  float q0[10] = {msgs0, msgsv0, dv0x, dv0y, dv0z, dt00, dt01, dt02, dt03, dt04};
  float q1[10] = {msgs1, msgsv1, dv1x, dv1y, dv1z, dt10, dt11, dt12, dt13, dt14};
  #pragma unroll
  for (int k = 0; k < 10; ++k) { q0[k] = wred(q0[k]); q1[k] = wred(q1[k]); }
  if (g == 0) {
    float* w0 = ws + (size_t)bx * 1280;
    #pragma unroll
    for (int k = 0; k < 10; ++k) {
      w0[k*128 + c0] = q0[k];
      w0[k*128 + c1] = q1[k];
    }
  }
}

// ---------------- final combine ----------------------------------------
template<int NSPLIT>
__global__ __launch_bounds__(256) void cg_final(
    const float* __restrict__ ws,
    const float* __restrict__ ln_g, const float* __restrict__ ln_b,
    const float* __restrict__ Wo, const float* __restrict__ bo,
    const float* __restrict__ v_scale, const float* __restrict__ t_scale,
    float* __restrict__ out)
{
  __shared__ float Xv[128];
  __shared__ float XN[128];
  __shared__ float PS[2][128];
  __shared__ float ST[2];
  const int bi = blockIdx.x;
  const int tid = threadIdx.x;

  if (tid < 128) {
    float acc[10];
    #pragma unroll
    for (int k = 0; k < 10; ++k) acc[k] = 0.f;
    #pragma unroll
    for (int q = 0; q < NSPLIT; ++q) {
      const float* pa = ws + ((size_t)bi * NSPLIT + q) * 1280;
      #pragma unroll
      for (int k = 0; k < 10; ++k) acc[k] += pa[k*128 + tid];
    }
    float vs = v_scale[tid], ts = t_scale[tid];
    size_t vbase = 98304 + (size_t)bi * (3 * DD) + tid;
    out[vbase]        = acc[2] * vs;
    out[vbase + DD]   = acc[3] * vs;
    out[vbase + 2*DD] = acc[4] * vs;
    size_t tbase = 393216 + (size_t)bi * (5 * DD) + tid;
    out[tbase]        = acc[5] * ts;
    out[tbase + DD]   = acc[6] * ts;
    out[tbase + 2*DD] = acc[7] * ts;
    out[tbase + 3*DD] = acc[8] * ts;
    out[tbase + 4*DD] = acc[9] * ts;
    Xv[tid] = acc[0] + acc[1];
  }
  __syncthreads();
  if (tid < 64) {
    float a = Xv[tid], c = Xv[tid + 64];
    float s = a + c, ss = a*a + c*c;
    #pragma unroll
    for (int off = 32; off > 0; off >>= 1) {
      s  += __shfl_down(s, off);
      ss += __shfl_down(ss, off);
    }
    if (tid == 0) {
      float mu  = s * (1.f / 128.f);
      float var = ss * (1.f / 128.f) - mu * mu;
      ST[0] = mu; ST[1] = rsqrtf(var + 1e-5f);
    }
  }
  __syncthreads();
  if (tid < 128) XN[tid] = (Xv[tid] - ST[0]) * ST[1] * ln_g[tid] + ln_b[tid];
  __syncthreads();
  {
    int dp = tid & 127, p = tid >> 7;
    float s = 0.f;
    #pragma unroll
    for (int dd = 0; dd < 64; ++dd) {
      int d = p * 64 + dd;
      s += XN[d] * Wo[d * DD + dp];
    }
    PS[p][dp] = s;
  }
  __syncthreads();
  if (tid < 128)
    out[(size_t)bi * DD + tid] = PS[0][tid] + PS[1][tid] + bo[tid];
}

extern "C" void kernel_launch(void* const* d_in, const int* in_sizes, int n_in,
                              void* d_out, int out_size, void* d_ws, size_t ws_size,
                              hipStream_t stream) {
  (void)in_sizes; (void)n_in; (void)out_size;
  const float* node_s = (const float*)d_in[0];
  const float* node_v = (const float*)d_in[1];
  const float* rbf    = (const float*)d_in[3];
  const float* r_hat  = (const float*)d_in[4];
  const float* mask   = (const float*)d_in[5];
  const float* Ws1 = (const float*)d_in[6];  const float* bs1 = (const float*)d_in[7];
  const float* Ws2 = (const float*)d_in[8];  const float* bs2 = (const float*)d_in[9];
  const float* Wd1 = (const float*)d_in[10]; const float* bd1 = (const float*)d_in[11];
  const float* Wd2 = (const float*)d_in[12]; const float* bd2 = (const float*)d_in[13];
  const float* Wv1 = (const float*)d_in[14]; const float* bv1 = (const float*)d_in[15];
  const float* Wv2 = (const float*)d_in[16]; const float* bv2 = (const float*)d_in[17];
  const float* Wt1 = (const float*)d_in[18]; const float* bt1 = (const float*)d_in[19];
  const float* Wt2 = (const float*)d_in[20]; const float* bt2 = (const float*)d_in[21];
  const float* ln_g = (const float*)d_in[22]; const float* ln_b = (const float*)d_in[23];
  const float* Wo   = (const float*)d_in[24]; const float* bo   = (const float*)d_in[25];
  const float* v_scale = (const float*)d_in[26];
  const float* t_scale = (const float*)d_in[27];
  float* outp = (float*)d_out;

  // ws layout: [partials f32][w1f bf16 16384][w2f bf16 65536][bcat1 512 f32][bcat2 512 f32]
  const size_t wtail = 16384ull*2 + 65536ull*2 + 1024ull*4;   // 168 KB
  const size_t need4 = 3072ull * 1280 * 4 + wtail;
  char* wsb = (char*)d_ws;

  bool use4 = (ws_size >= need4);
  size_t pbytes = use4 ? 3072ull * 1280 * 4 : 1536ull * 1280 * 4;
  float* partials = (float*)wsb;
  unsigned short* w1f = (unsigned short*)(wsb + pbytes);
  unsigned short* w2f = w1f + 16384;
  float* bcat1 = (float*)(w2f + 65536);
  float* bcat2 = bcat1 + 512;

  hipLaunchKernelGGL(cg_prep, dim3(44), dim3(256), 0, stream,
                     Ws1, Wd1, Wv1, Wt1, Ws2, Wd2, Wv2, Wt2,
                     bs1, bd1, bv1, bt1, bs2, bd2, bv2, bt2,
                     w1f, w2f, bcat1, bcat2);

  if (use4) {
    hipLaunchKernelGGL((cg_main<48, 4>), dim3(4 * 768), dim3(256), 0, stream,
                       node_s, node_v, rbf, r_hat, mask,
                       w1f, w2f, bcat1, bcat2, partials);
    hipLaunchKernelGGL((cg_final<4>), dim3(768), dim3(256), 0, stream,
                       partials, ln_g, ln_b, Wo, bo, v_scale, t_scale, outp);
  } else {
    hipLaunchKernelGGL((cg_main<96, 2>), dim3(2 * 768), dim3(256), 0, stream,
                       node_s, node_v, rbf, r_hat, mask,
                       w1f, w2f, bcat1, bcat2, partials);
    hipLaunchKernelGGL((cg_final<2>), dim3(768), dim3(256), 0, stream,
                       partials, ln_g, ln_b, Wo, bo, v_scale, t_scale, outp);
  }
}